// Round 1
// baseline (342.396 us; speedup 1.0000x reference)
//
#include <hip/hip_runtime.h>
#include <hip/hip_bf16.h>
#include <stdint.h>

#define M_DIM 8192
#define K_DIM 2048
#define N_DIM 4096
#define NTILES (N_DIM / 128)   // 32
#define MTILES (M_DIM / 128)   // 64

typedef __hip_bfloat16 bf16;
typedef __attribute__((ext_vector_type(8))) short bf16x8;
typedef __attribute__((ext_vector_type(4))) float floatx4;

__device__ __forceinline__ void gload_lds16(const void* g, void* l) {
  __builtin_amdgcn_global_load_lds((const __attribute__((address_space(1))) void*)g,
                                   (__attribute__((address_space(3))) void*)l, 16, 0, 0);
}

// ---------------- Kernel 0: fp32 -> bf16 convert (x then W), 8 elems/thread ----
__global__ __launch_bounds__(256) void convert_kernel(
    const float* __restrict__ x, const float* __restrict__ W,
    bf16* __restrict__ xb, bf16* __restrict__ wb) {
  int idx = blockIdx.x * 256 + threadIdx.x;
  int e = idx * 8;
  const int NX = M_DIM * K_DIM;  // 16,777,216
  const float* src;
  bf16* dst;
  if (e < NX) { src = x + e; dst = xb + e; }
  else        { src = W + (e - NX); dst = wb + (e - NX); }
  const float4* s4 = (const float4*)src;
  float4 a = s4[0];
  float4 c = s4[1];
  union { bf16 h[8]; uint4 u; } o;
  o.h[0] = __float2bfloat16(a.x); o.h[1] = __float2bfloat16(a.y);
  o.h[2] = __float2bfloat16(a.z); o.h[3] = __float2bfloat16(a.w);
  o.h[4] = __float2bfloat16(c.x); o.h[5] = __float2bfloat16(c.y);
  o.h[6] = __float2bfloat16(c.z); o.h[7] = __float2bfloat16(c.w);
  *(uint4*)dst = o.u;
}

// ---------------- Kernel 1: GEMM (computes C^T tile) + bias + groupnorm + min --
// Block computes 128 n-rows x 128 m-cols of y^T. MFMA A-operand = W rows (n),
// B-operand = x rows (m). C/D layout: D[row=n][col=m], row=(lane>>4)*4+reg,
// col=lane&15 -> 4 consecutive n per lane => group-of-8 stats = 1 shfl_xor(16).
__global__ __launch_bounds__(256, 2) void gemm_gn_min(
    const bf16* __restrict__ xb, const bf16* __restrict__ wb,
    const float* __restrict__ bgemm, float* __restrict__ pmin) {
  __shared__ bf16 As[128 * 64];      // x tile  [m-row][k]
  __shared__ bf16 Bs[128 * 64];      // W tile  [n-row][k]
  __shared__ float smin[2][128];

  const int tid = threadIdx.x;
  const int lane = tid & 63;
  const int wv = tid >> 6;           // 0..3
  const int waveN = wv >> 1;         // n-block half (rows of C^T)
  const int waveM = wv & 1;          // m-block half (cols of C^T)

  const int mTile = blockIdx.x & (MTILES - 1);
  const int nTile = blockIdx.x >> 6;
  const int mBase = mTile * 128;
  const int nBase = nTile * 128;

  // staging map: lane -> (row-in-8-chunk, xor-swizzled k-chunk)
  const int ldRow = lane >> 3;                    // 0..7
  const int ldCol = ((lane & 7) ^ ldRow) * 8;     // swizzle on GLOBAL col

  const int q = lane >> 4;   // quad 0..3
  const int c = lane & 15;

  floatx4 acc[4][4];
#pragma unroll
  for (int i = 0; i < 4; ++i)
#pragma unroll
    for (int j = 0; j < 4; ++j) acc[i][j] = (floatx4){0.f, 0.f, 0.f, 0.f};

  const bf16* xg = xb + mBase * K_DIM + ldCol;
  const bf16* wg = wb + nBase * K_DIM + ldCol;

  for (int k0 = 0; k0 < K_DIM; k0 += 64) {
    __syncthreads();                  // protect LDS from previous iter's reads
#pragma unroll
    for (int i = 0; i < 4; ++i) {
      int chunk = i * 4 + wv;         // 0..15 (8 rows each); wave-uniform
      int row = chunk * 8 + ldRow;    // 0..127
      gload_lds16(xg + row * K_DIM + k0, (void*)(As + chunk * 512));
      gload_lds16(wg + row * K_DIM + k0, (void*)(Bs + chunk * 512));
    }
    __syncthreads();
#pragma unroll
    for (int ks = 0; ks < 2; ++ks) {
      bf16x8 af[4], bfr[4];
#pragma unroll
      for (int i = 0; i < 4; ++i) {       // A-operand: W rows (n)
        int row = waveN * 64 + i * 16 + c;
        int chunk = (ks * 4 + q) ^ (row & 7);
        af[i] = *(const bf16x8*)(Bs + row * 64 + chunk * 8);
      }
#pragma unroll
      for (int j = 0; j < 4; ++j) {       // B-operand: x rows (m)
        int row = waveM * 64 + j * 16 + c;
        int chunk = (ks * 4 + q) ^ (row & 7);
        bfr[j] = *(const bf16x8*)(As + row * 64 + chunk * 8);
      }
#pragma unroll
      for (int i = 0; i < 4; ++i)
#pragma unroll
        for (int j = 0; j < 4; ++j)
          acc[i][j] = __builtin_amdgcn_mfma_f32_16x16x32_bf16(af[i], bfr[j], acc[i][j], 0, 0, 0);
    }
  }

  // ---- epilogue: +b, groupnorm over 8 consecutive n, min over n per col m ----
  float bv[4][4];
#pragma unroll
  for (int i = 0; i < 4; ++i)
#pragma unroll
    for (int r = 0; r < 4; ++r)
      bv[i][r] = bgemm[nBase + waveN * 64 + i * 16 + q * 4 + r];

  float colmin[4] = {3.4e38f, 3.4e38f, 3.4e38f, 3.4e38f};
#pragma unroll
  for (int i = 0; i < 4; ++i) {
#pragma unroll
    for (int j = 0; j < 4; ++j) {
      float v0 = acc[i][j][0] + bv[i][0];
      float v1 = acc[i][j][1] + bv[i][1];
      float v2 = acc[i][j][2] + bv[i][2];
      float v3 = acc[i][j][3] + bv[i][3];
      float s  = (v0 + v1) + (v2 + v3);
      float ss = (v0 * v0 + v1 * v1) + (v2 * v2 + v3 * v3);
      // partner quad (lane^16) holds the other 4 n's of this group of 8
      s  += __shfl_xor(s, 16);
      ss += __shfl_xor(ss, 16);
      float mean = s * 0.125f;
      float var  = ss * 0.125f - mean * mean;
      float inv  = rsqrtf(var + 1e-5f);          // inv > 0, so min commutes
      float mndev = fminf(fminf(v0, v1), fminf(v2, v3)) - mean;
      colmin[j] = fminf(colmin[j], mndev * inv);
    }
  }
  // reduce over quads: lanes sharing col c cover all 64 n-rows of this wave
#pragma unroll
  for (int j = 0; j < 4; ++j) {
    float m0 = colmin[j];
    m0 = fminf(m0, __shfl_xor(m0, 16));
    m0 = fminf(m0, __shfl_xor(m0, 32));
    colmin[j] = m0;
  }
  if (q == 0) {
#pragma unroll
    for (int j = 0; j < 4; ++j)
      smin[waveN][waveM * 64 + j * 16 + c] = colmin[j];
  }
  __syncthreads();
  if (tid < 128) {
    float p = fminf(smin[0][tid], smin[1][tid]);
    pmin[(mBase + tid) * NTILES + nTile] = p;   // one writer per slot
  }
}

// ---------------- Kernel 2: out[m, n] = rowmin[m] + bias[n] -------------------
__global__ __launch_bounds__(256) void out_kernel(
    const float* __restrict__ pmin, const float* __restrict__ bias,
    float* __restrict__ out) {
  const int m = blockIdx.x;
  const int tid = threadIdx.x;
  __shared__ float srow;
  if (tid < 64) {
    float v = (tid < NTILES) ? pmin[m * NTILES + tid] : 3.4e38f;
    v = fminf(v, __shfl_xor(v, 1));
    v = fminf(v, __shfl_xor(v, 2));
    v = fminf(v, __shfl_xor(v, 4));
    v = fminf(v, __shfl_xor(v, 8));
    v = fminf(v, __shfl_xor(v, 16));
    if (tid == 0) srow = v;
  }
  __syncthreads();
  const float rmin = srow;
  const float4* b4 = (const float4*)bias;
  float4* o4 = (float4*)(out + (size_t)m * N_DIM);
#pragma unroll
  for (int it = 0; it < 4; ++it) {
    int idx2 = it * 256 + tid;
    float4 bb = b4[idx2];
    o4[idx2] = (float4){rmin + bb.x, rmin + bb.y, rmin + bb.z, rmin + bb.w};
  }
}

extern "C" void kernel_launch(void* const* d_in, const int* in_sizes, int n_in,
                              void* d_out, int out_size, void* d_ws, size_t ws_size,
                              hipStream_t stream) {
  const float* x    = (const float*)d_in[0];
  const float* W    = (const float*)d_in[1];
  const float* b    = (const float*)d_in[2];
  const float* bias = (const float*)d_in[3];
  float* out = (float*)d_out;

  // bf16 scratch lives in d_out (134 MB >> 50 MB needed); overwritten at the end.
  bf16* xb = (bf16*)d_out;
  bf16* wb = (bf16*)((char*)d_out + (size_t)M_DIM * K_DIM * sizeof(bf16));
  float* pmin = (float*)d_ws;  // 8192 * 32 * 4 = 1 MiB of workspace

  convert_kernel<<<(M_DIM * K_DIM + N_DIM * K_DIM) / (8 * 256), 256, 0, stream>>>(x, W, xb, wb);
  gemm_gn_min<<<MTILES * NTILES, 256, 0, stream>>>(xb, wb, b, pmin);
  out_kernel<<<M_DIM, 256, 0, stream>>>(pmin, bias, out);
}